// Round 1
// baseline (999.033 us; speedup 1.0000x reference)
//
#include <hip/hip_runtime.h>
#include <hip/hip_bf16.h>
#include <math.h>

typedef __attribute__((ext_vector_type(8))) short short8;
typedef __attribute__((ext_vector_type(4))) float f32x4;

#define C_DIM 1024
#define T_DIM 2048
#define NH 16
#define HD 64
#define NTOK 4096

__device__ __forceinline__ unsigned short f2bf(float f) {
  unsigned u = __float_as_uint(f);
  u += 0x7fffu + ((u >> 16) & 1u);
  return (unsigned short)(u >> 16);
}

__device__ __forceinline__ void bf8_to_f32(uint4 u, float* d) {
  d[0] = __uint_as_float(u.x << 16); d[1] = __uint_as_float(u.x & 0xffff0000u);
  d[2] = __uint_as_float(u.y << 16); d[3] = __uint_as_float(u.y & 0xffff0000u);
  d[4] = __uint_as_float(u.z << 16); d[5] = __uint_as_float(u.z & 0xffff0000u);
  d[6] = __uint_as_float(u.w << 16); d[7] = __uint_as_float(u.w & 0xffff0000u);
}

// ---------------- LayerNorm: fp32 [rows,1024] -> bf16 ----------------
__global__ __launch_bounds__(256) void ln_kernel(
    const float* __restrict__ x, const float* __restrict__ g,
    const float* __restrict__ b, unsigned short* __restrict__ out) {
  int row = blockIdx.x;
  int tid = threadIdx.x;
  const float4* xr = (const float4*)(x + (size_t)row * C_DIM);
  float4 v = xr[tid];
  float s = v.x + v.y + v.z + v.w;
  float ss = v.x * v.x + v.y * v.y + v.z * v.z + v.w * v.w;
#pragma unroll
  for (int off = 32; off; off >>= 1) {
    s += __shfl_down(s, off);
    ss += __shfl_down(ss, off);
  }
  __shared__ float red[8];
  if ((tid & 63) == 0) { red[tid >> 6] = s; red[4 + (tid >> 6)] = ss; }
  __syncthreads();
  float S = red[0] + red[1] + red[2] + red[3];
  float SS = red[4] + red[5] + red[6] + red[7];
  float mu = S * (1.0f / C_DIM);
  float var = SS * (1.0f / C_DIM) - mu * mu;
  float rs = rsqrtf(var + 1e-5f);
  float4 gg = ((const float4*)g)[tid];
  float4 bb = ((const float4*)b)[tid];
  ushort4 o;
  o.x = f2bf((v.x - mu) * rs * gg.x + bb.x);
  o.y = f2bf((v.y - mu) * rs * gg.y + bb.y);
  o.z = f2bf((v.z - mu) * rs * gg.z + bb.z);
  o.w = f2bf((v.w - mu) * rs * gg.w + bb.w);
  *(ushort4*)(out + (size_t)row * C_DIM + tid * 4) = o;
}

// ------------- weight transpose+cast: W[K][N] fp32 -> Wt[N][K] bf16 -------------
__global__ __launch_bounds__(256) void wt_kernel(
    const float* __restrict__ W, unsigned short* __restrict__ Wt, int K, int N) {
  __shared__ float t[32][33];
  int n0 = blockIdx.x * 32, k0 = blockIdx.y * 32;
  int tx = threadIdx.x, ty = threadIdx.y;
#pragma unroll
  for (int j = 0; j < 4; j++)
    t[ty + j * 8][tx] = W[(size_t)(k0 + ty + j * 8) * N + n0 + tx];
  __syncthreads();
#pragma unroll
  for (int j = 0; j < 4; j++)
    Wt[(size_t)(n0 + ty + j * 8) * K + k0 + tx] = f2bf(t[tx][ty + j * 8]);
}

// ------------- GEMM: C[M,N] = act(A[M,K] * Bt[N,K]^T + bias) (+res) -------------
// A,Bt bf16 row-major, bias fp32, res fp32 or null; OUTBF: bf16 out else fp32.
template <int ACT, int OUTBF>
__global__ __launch_bounds__(256) void gemm_bt(
    const unsigned short* __restrict__ A, const unsigned short* __restrict__ Bt,
    const float* __restrict__ bias, const float* __restrict__ res,
    void* __restrict__ Cout, int M, int N, int K) {
  __shared__ short sA[128 * 32];
  __shared__ short sB[128 * 32];
  int tid = threadIdx.x;
  int wave = tid >> 6, lane = tid & 63;
  int l16 = lane & 15, quad = lane >> 4;
  int row0 = blockIdx.y * 128, col0 = blockIdx.x * 128;
  int wm = (wave & 1) * 64, wn = (wave >> 1) * 64;
  f32x4 acc[4][4];
#pragma unroll
  for (int i = 0; i < 4; i++)
#pragma unroll
    for (int j = 0; j < 4; j++) acc[i][j] = (f32x4){0.f, 0.f, 0.f, 0.f};

  for (int k0 = 0; k0 < K; k0 += 32) {
#pragma unroll
    for (int i = 0; i < 2; i++) {
      int c = tid + i * 256;  // 512 16B-chunks per tile
      int r = c >> 2, cc = (c & 3) * 8;
      *(uint4*)&sA[r * 32 + cc] = *(const uint4*)(A + (size_t)(row0 + r) * K + k0 + cc);
      *(uint4*)&sB[r * 32 + cc] = *(const uint4*)(Bt + (size_t)(col0 + r) * K + k0 + cc);
    }
    __syncthreads();
    short8 a[4], b[4];
#pragma unroll
    for (int i = 0; i < 4; i++) {
      a[i] = *(const short8*)&sA[(wm + i * 16 + l16) * 32 + quad * 8];
      b[i] = *(const short8*)&sB[(wn + i * 16 + l16) * 32 + quad * 8];
    }
#pragma unroll
    for (int mi = 0; mi < 4; mi++)
#pragma unroll
      for (int ni = 0; ni < 4; ni++)
        acc[mi][ni] = __builtin_amdgcn_mfma_f32_16x16x32_bf16(a[mi], b[ni], acc[mi][ni], 0, 0, 0);
    __syncthreads();
  }
#pragma unroll
  for (int mi = 0; mi < 4; mi++) {
#pragma unroll
    for (int ni = 0; ni < 4; ni++) {
      int col = col0 + wn + ni * 16 + l16;
      float bv = bias[col];
#pragma unroll
      for (int i = 0; i < 4; i++) {
        int row = row0 + wm + mi * 16 + quad * 4 + i;
        float v = acc[mi][ni][i] + bv;
        if (ACT == 1) v = 0.5f * v * (1.0f + erff(v * 0.7071067811865475f));
        if (res) v += res[(size_t)row * N + col];
        if (OUTBF)
          ((unsigned short*)Cout)[(size_t)row * N + col] = f2bf(v);
        else
          ((float*)Cout)[(size_t)row * N + col] = v;
      }
    }
  }
}

// ------------- split qkv [4096,3072] bf16 -> per-head Q,K,V [32][2048][64] -------------
__global__ __launch_bounds__(256) void qkv_split_kernel(
    const unsigned short* __restrict__ qkv, unsigned short* __restrict__ Qh,
    unsigned short* __restrict__ Kh, unsigned short* __restrict__ Vh) {
  int idx = blockIdx.x * 256 + threadIdx.x;
  int row = idx / 3072;
  int col = idx - row * 3072;
  int which = col >> 10;
  int h = (col & 1023) >> 6;
  int d = col & 63;
  int b = row >> 11, t = row & 2047;
  size_t off = (((size_t)(b * NH + h)) * T_DIM + t) * HD + d;
  unsigned short v = qkv[idx];
  if (which == 0) Qh[off] = v;
  else if (which == 1) Kh[off] = v;
  else Vh[off] = v;
}

// ------------- causal flash attention (VALU), per block: 1 head x 32 q rows -------------
#define TQ 32
#define TKV 64
__global__ __launch_bounds__(256) void attn_kernel(
    const unsigned short* __restrict__ Qh, const unsigned short* __restrict__ Kh,
    const unsigned short* __restrict__ Vh, unsigned short* __restrict__ Y) {
  __shared__ float sK[TKV][68];
  __shared__ float sV[TKV][68];
  __shared__ float sP[TQ][68];
  int head = blockIdx.y;
  int q0 = (gridDim.x - 1 - blockIdx.x) * TQ;  // reversed: big blocks first
  int tid = threadIdx.x;
  int wave = tid >> 6, lane = tid & 63;
  int rl = lane >> 3, sub = lane & 7;
  int row_local = wave * 8 + rl;  // [0,32)
  int r = q0 + row_local;         // q row within head

  float q[64];
  {
    const uint4* qp = (const uint4*)(Qh + ((size_t)head * T_DIM + r) * HD);
#pragma unroll
    for (int c = 0; c < 8; c++) bf8_to_f32(qp[c], &q[c * 8]);
  }
  float o[8] = {0, 0, 0, 0, 0, 0, 0, 0};
  float m = -1e30f, l = 0.0f;
  int ntiles = (q0 + TQ + TKV - 1) / TKV;
  const unsigned short* Kbase = Kh + (size_t)head * T_DIM * HD;
  const unsigned short* Vbase = Vh + (size_t)head * T_DIM * HD;

  for (int t = 0; t < ntiles; t++) {
    int kv0 = t * TKV;
#pragma unroll
    for (int i = 0; i < 2; i++) {
      int ch = tid + i * 256;            // 512 chunks of 16B per matrix
      int krow = ch >> 3, cc = (ch & 7) * 8;
      uint4 uk = *(const uint4*)(Kbase + (size_t)(kv0 + krow) * HD + cc);
      uint4 uv = *(const uint4*)(Vbase + (size_t)(kv0 + krow) * HD + cc);
      bf8_to_f32(uk, &sK[krow][cc]);
      bf8_to_f32(uv, &sV[krow][cc]);
    }
    __syncthreads();

    float s[8];
#pragma unroll
    for (int i = 0; i < 8; i++) {
      const float* kp = &sK[sub + i * 8][0];
      float a0 = 0, a1 = 0, a2 = 0, a3 = 0;
#pragma unroll
      for (int d = 0; d < 64; d += 4) {
        a0 += q[d] * kp[d];
        a1 += q[d + 1] * kp[d + 1];
        a2 += q[d + 2] * kp[d + 2];
        a3 += q[d + 3] * kp[d + 3];
      }
      float acc = (a0 + a1) + (a2 + a3);
      s[i] = (kv0 + sub + i * 8 <= r) ? acc * 0.125f : -1e30f;
    }
    float tmax = s[0];
#pragma unroll
    for (int i = 1; i < 8; i++) tmax = fmaxf(tmax, s[i]);
#pragma unroll
    for (int off = 1; off < 8; off <<= 1) tmax = fmaxf(tmax, __shfl_xor(tmax, off));
    float mnew = fmaxf(m, tmax);
    float alpha = __expf(m - mnew);
    float psum = 0.f;
#pragma unroll
    for (int i = 0; i < 8; i++) { s[i] = __expf(s[i] - mnew); psum += s[i]; }
#pragma unroll
    for (int off = 1; off < 8; off <<= 1) psum += __shfl_xor(psum, off);
    l = l * alpha + psum;
    m = mnew;
#pragma unroll
    for (int i = 0; i < 8; i++) sP[row_local][sub + i * 8] = s[i];
#pragma unroll
    for (int j = 0; j < 8; j++) o[j] *= alpha;
    __syncthreads();
#pragma unroll 8
    for (int kv = 0; kv < TKV; kv++) {
      float p = sP[row_local][kv];
      const float* vr = &sV[kv][sub * 8];
#pragma unroll
      for (int j = 0; j < 8; j++) o[j] += p * vr[j];
    }
    __syncthreads();
  }
  float invl = 1.0f / l;
  int b = head >> 4, h = head & 15;
  unsigned short ob[8];
#pragma unroll
  for (int j = 0; j < 8; j++) ob[j] = f2bf(o[j] * invl);
  uint4 w;
  w.x = ((unsigned)ob[1] << 16) | ob[0];
  w.y = ((unsigned)ob[3] << 16) | ob[2];
  w.z = ((unsigned)ob[5] << 16) | ob[4];
  w.w = ((unsigned)ob[7] << 16) | ob[6];
  *(uint4*)(Y + ((size_t)(b * T_DIM + r)) * C_DIM + h * HD + sub * 8) = w;
}

extern "C" void kernel_launch(void* const* d_in, const int* in_sizes, int n_in,
                              void* d_out, int out_size, void* d_ws, size_t ws_size,
                              hipStream_t stream) {
  const float* x      = (const float*)d_in[0];
  const float* ln1_g  = (const float*)d_in[1];
  const float* ln1_b  = (const float*)d_in[2];
  const float* attn_w = (const float*)d_in[3];
  const float* attn_b = (const float*)d_in[4];
  const float* proj_w = (const float*)d_in[5];
  const float* proj_b = (const float*)d_in[6];
  const float* ln2_g  = (const float*)d_in[7];
  const float* ln2_b  = (const float*)d_in[8];
  const float* fc_w   = (const float*)d_in[9];
  const float* fc_b   = (const float*)d_in[10];
  const float* fc2_w  = (const float*)d_in[11];
  const float* fc2_b  = (const float*)d_in[12];

  char* ws = (char*)d_ws;
  unsigned short* wqkv_t  = (unsigned short*)(ws + 0);          // 6 MB
  unsigned short* wproj_t = (unsigned short*)(ws + 6291456);    // 2 MB
  unsigned short* wfc_t   = (unsigned short*)(ws + 8388608);    // 8 MB
  unsigned short* wfc2_t  = (unsigned short*)(ws + 16777216);   // 8 MB
  unsigned short* xn1     = (unsigned short*)(ws + 25165824);   // 8 MB (reused as xn2)
  unsigned short* qkv     = (unsigned short*)(ws + 33554432);   // 24 MB
  unsigned short* Qh      = (unsigned short*)(ws + 58720256);   // 8 MB
  unsigned short* Kh      = (unsigned short*)(ws + 67108864);   // 8 MB
  unsigned short* Vh      = (unsigned short*)(ws + 75497472);   // 8 MB -> peak 80 MB
  unsigned short* y       = (unsigned short*)(ws + 33554432);   // alias qkv head (dead)
  unsigned short* hmid    = (unsigned short*)(ws + 41943040);   // alias qkv tail+Qh+Kh (dead)
  unsigned short* xn2     = xn1;                                // alias (xn1 dead)
  float* x1  = (float*)d_out;  // residual-1 result lives in d_out
  float* out = (float*)d_out;

  dim3 t32x8(32, 8);
  wt_kernel<<<dim3(3072 / 32, 1024 / 32), t32x8, 0, stream>>>(attn_w, wqkv_t, 1024, 3072);
  wt_kernel<<<dim3(1024 / 32, 1024 / 32), t32x8, 0, stream>>>(proj_w, wproj_t, 1024, 1024);
  wt_kernel<<<dim3(4096 / 32, 1024 / 32), t32x8, 0, stream>>>(fc_w, wfc_t, 1024, 4096);
  wt_kernel<<<dim3(1024 / 32, 4096 / 32), t32x8, 0, stream>>>(fc2_w, wfc2_t, 4096, 1024);

  ln_kernel<<<NTOK, 256, 0, stream>>>(x, ln1_g, ln1_b, xn1);
  gemm_bt<0, 1><<<dim3(3072 / 128, NTOK / 128), 256, 0, stream>>>(
      xn1, wqkv_t, attn_b, nullptr, qkv, NTOK, 3072, 1024);
  qkv_split_kernel<<<NTOK * 3072 / 256, 256, 0, stream>>>(qkv, Qh, Kh, Vh);
  attn_kernel<<<dim3(T_DIM / TQ, 32), 256, 0, stream>>>(Qh, Kh, Vh, y);
  gemm_bt<0, 0><<<dim3(1024 / 128, NTOK / 128), 256, 0, stream>>>(
      y, wproj_t, proj_b, x, (void*)x1, NTOK, 1024, 1024);
  ln_kernel<<<NTOK, 256, 0, stream>>>(x1, ln2_g, ln2_b, xn2);
  gemm_bt<1, 1><<<dim3(4096 / 128, NTOK / 128), 256, 0, stream>>>(
      xn2, wfc_t, fc_b, nullptr, hmid, NTOK, 4096, 1024);
  gemm_bt<0, 0><<<dim3(1024 / 128, NTOK / 128), 256, 0, stream>>>(
      hmid, wfc2_t, fc2_b, x1, (void*)out, NTOK, 1024, 4096);
}

// Round 2
// 493.197 us; speedup vs baseline: 2.0256x; 2.0256x over previous
//
#include <hip/hip_runtime.h>
#include <hip/hip_bf16.h>
#include <math.h>

typedef __attribute__((ext_vector_type(8))) short short8;
typedef __attribute__((ext_vector_type(4))) float f32x4;

#define C_DIM 1024
#define T_DIM 2048
#define NH 16
#define HD 64
#define NTOK 4096

__device__ __forceinline__ unsigned short f2bf(float f) {
  unsigned u = __float_as_uint(f);
  u += 0x7fffu + ((u >> 16) & 1u);
  return (unsigned short)(u >> 16);
}

// ---------------- LayerNorm: fp32 [rows,1024] -> bf16 ----------------
__global__ __launch_bounds__(256) void ln_kernel(
    const float* __restrict__ x, const float* __restrict__ g,
    const float* __restrict__ b, unsigned short* __restrict__ out) {
  int row = blockIdx.x;
  int tid = threadIdx.x;
  const float4* xr = (const float4*)(x + (size_t)row * C_DIM);
  float4 v = xr[tid];
  float s = v.x + v.y + v.z + v.w;
  float ss = v.x * v.x + v.y * v.y + v.z * v.z + v.w * v.w;
#pragma unroll
  for (int off = 32; off; off >>= 1) {
    s += __shfl_down(s, off);
    ss += __shfl_down(ss, off);
  }
  __shared__ float red[8];
  if ((tid & 63) == 0) { red[tid >> 6] = s; red[4 + (tid >> 6)] = ss; }
  __syncthreads();
  float S = red[0] + red[1] + red[2] + red[3];
  float SS = red[4] + red[5] + red[6] + red[7];
  float mu = S * (1.0f / C_DIM);
  float var = SS * (1.0f / C_DIM) - mu * mu;
  float rs = rsqrtf(var + 1e-5f);
  float4 gg = ((const float4*)g)[tid];
  float4 bb = ((const float4*)b)[tid];
  ushort4 o;
  o.x = f2bf((v.x - mu) * rs * gg.x + bb.x);
  o.y = f2bf((v.y - mu) * rs * gg.y + bb.y);
  o.z = f2bf((v.z - mu) * rs * gg.z + bb.z);
  o.w = f2bf((v.w - mu) * rs * gg.w + bb.w);
  *(ushort4*)(out + (size_t)row * C_DIM + tid * 4) = o;
}

// ------------- weight transpose+cast: W[K][N] fp32 -> Wt[N][K] bf16 -------------
__global__ __launch_bounds__(256) void wt_kernel(
    const float* __restrict__ W, unsigned short* __restrict__ Wt, int K, int N) {
  __shared__ float t[32][33];
  int n0 = blockIdx.x * 32, k0 = blockIdx.y * 32;
  int tx = threadIdx.x, ty = threadIdx.y;
#pragma unroll
  for (int j = 0; j < 4; j++)
    t[ty + j * 8][tx] = W[(size_t)(k0 + ty + j * 8) * N + n0 + tx];
  __syncthreads();
#pragma unroll
  for (int j = 0; j < 4; j++)
    Wt[(size_t)(n0 + ty + j * 8) * K + k0 + tx] = f2bf(t[tx][ty + j * 8]);
}

// ------------- GEMM: C[M,N] = act(A[M,K] * Bt[N,K]^T + bias) (+res) -------------
template <int ACT, int OUTBF>
__global__ __launch_bounds__(256) void gemm_bt(
    const unsigned short* __restrict__ A, const unsigned short* __restrict__ Bt,
    const float* __restrict__ bias, const float* __restrict__ res,
    void* __restrict__ Cout, int M, int N, int K) {
  __shared__ short sA[128 * 32];
  __shared__ short sB[128 * 32];
  int tid = threadIdx.x;
  int wave = tid >> 6, lane = tid & 63;
  int l16 = lane & 15, quad = lane >> 4;
  int row0 = blockIdx.y * 128, col0 = blockIdx.x * 128;
  int wm = (wave & 1) * 64, wn = (wave >> 1) * 64;
  f32x4 acc[4][4];
#pragma unroll
  for (int i = 0; i < 4; i++)
#pragma unroll
    for (int j = 0; j < 4; j++) acc[i][j] = (f32x4){0.f, 0.f, 0.f, 0.f};

  for (int k0 = 0; k0 < K; k0 += 32) {
#pragma unroll
    for (int i = 0; i < 2; i++) {
      int c = tid + i * 256;
      int r = c >> 2, cc = (c & 3) * 8;
      *(uint4*)&sA[r * 32 + cc] = *(const uint4*)(A + (size_t)(row0 + r) * K + k0 + cc);
      *(uint4*)&sB[r * 32 + cc] = *(const uint4*)(Bt + (size_t)(col0 + r) * K + k0 + cc);
    }
    __syncthreads();
    short8 a[4], b[4];
#pragma unroll
    for (int i = 0; i < 4; i++) {
      a[i] = *(const short8*)&sA[(wm + i * 16 + l16) * 32 + quad * 8];
      b[i] = *(const short8*)&sB[(wn + i * 16 + l16) * 32 + quad * 8];
    }
#pragma unroll
    for (int mi = 0; mi < 4; mi++)
#pragma unroll
      for (int ni = 0; ni < 4; ni++)
        acc[mi][ni] = __builtin_amdgcn_mfma_f32_16x16x32_bf16(a[mi], b[ni], acc[mi][ni], 0, 0, 0);
    __syncthreads();
  }
#pragma unroll
  for (int mi = 0; mi < 4; mi++) {
#pragma unroll
    for (int ni = 0; ni < 4; ni++) {
      int col = col0 + wn + ni * 16 + l16;
      float bv = bias[col];
#pragma unroll
      for (int i = 0; i < 4; i++) {
        int row = row0 + wm + mi * 16 + quad * 4 + i;
        float v = acc[mi][ni][i] + bv;
        if (ACT == 1) v = 0.5f * v * (1.0f + erff(v * 0.7071067811865475f));
        if (res) v += res[(size_t)row * N + col];
        if (OUTBF)
          ((unsigned short*)Cout)[(size_t)row * N + col] = f2bf(v);
        else
          ((float*)Cout)[(size_t)row * N + col] = v;
      }
    }
  }
}

// ------------- MFMA causal flash attention -------------
// Block: 4 waves, 64 q-rows (16/wave), one (b,h). KV tiles of 64.
// S^T = K·Q^T (q = lane&15 -> softmax row per-lane, reduce over quads).
// P stored [q][kv] bf16 (= A-layout for PV), V staged transposed Vt[d][kv].
#define AP 72  // LDS pitch (elems) for sK/sVt/sP: 144B rows, 16B-aligned
__global__ __launch_bounds__(256) void attn_mfma_kernel(
    const unsigned short* __restrict__ qkv, unsigned short* __restrict__ Y) {
  __shared__ short sK[64 * AP];
  __shared__ short sVt[64 * AP];
  __shared__ short sP[4][16 * AP];
  int qt = gridDim.x - 1 - blockIdx.x;  // reversed: most work first
  int hb = blockIdx.y;
  int bb = hb >> 4, h = hb & 15;
  int tid = threadIdx.x, wave = tid >> 6, lane = tid & 63;
  int l16 = lane & 15, quad = lane >> 4;
  int q0 = qt * 64, qbase = q0 + wave * 16;

  // Q B-frags in registers: Q[q=l16][d=quad*8+j], 2 k-chunks
  const unsigned short* qrow = qkv + (size_t)(bb * T_DIM + qbase + l16) * 3072 + h * HD;
  short8 qf[2];
  qf[0] = *(const short8*)(qrow + quad * 8);
  qf[1] = *(const short8*)(qrow + 32 + quad * 8);

  f32x4 o[4];
#pragma unroll
  for (int i = 0; i < 4; i++) o[i] = (f32x4){0.f, 0.f, 0.f, 0.f};
  float m = -1e30f, l = 0.f;

  const unsigned short* Kbase = qkv + (size_t)bb * T_DIM * 3072 + C_DIM + h * HD;
  const unsigned short* Vbase = Kbase + C_DIM;

  for (int kt = 0; kt <= qt; kt++) {
    int kv0 = kt * 64;
    // ---- stage K rows + V transposed ----
#pragma unroll
    for (int i = 0; i < 2; i++) {
      int c = tid + i * 256;
      int r = c >> 3, dcg = c & 7, dc = dcg * 8;
      uint4 kx = *(const uint4*)(Kbase + (size_t)(kv0 + r) * 3072 + dc);
      uint4 vx = *(const uint4*)(Vbase + (size_t)(kv0 + r) * 3072 + dc);
      *(uint4*)&sK[r * AP + dc] = kx;
      unsigned short ve[8];
      *(uint4*)ve = vx;
#pragma unroll
      for (int j = 0; j < 8; j++) {
        int jj = (j + r + dcg) & 7;  // rotation kills bank conflicts
        sVt[(dc + jj) * AP + r] = (short)ve[jj];
      }
    }
    __syncthreads();

    // ---- S^T = K·Q^T : M=kv(64), N=q(16), K=d(64) ----
    f32x4 st[4];
#pragma unroll
    for (int i = 0; i < 4; i++) st[i] = (f32x4){0.f, 0.f, 0.f, 0.f};
#pragma unroll
    for (int kc = 0; kc < 2; kc++)
#pragma unroll
      for (int mt = 0; mt < 4; mt++) {
        short8 af = *(const short8*)&sK[(mt * 16 + l16) * AP + kc * 32 + quad * 8];
        st[mt] = __builtin_amdgcn_mfma_f32_16x16x32_bf16(af, qf[kc], st[mt], 0, 0, 0);
      }

    // ---- mask + online softmax (row q = l16, spread over 4 quads) ----
    int qg = qbase + l16;
    float vals[16];
#pragma unroll
    for (int mt = 0; mt < 4; mt++)
#pragma unroll
      for (int r = 0; r < 4; r++) {
        int kv = kv0 + mt * 16 + quad * 4 + r;
        vals[mt * 4 + r] = (kv <= qg) ? st[mt][r] * 0.125f : -1e30f;
      }
    float mx = vals[0];
#pragma unroll
    for (int i = 1; i < 16; i++) mx = fmaxf(mx, vals[i]);
    mx = fmaxf(mx, __shfl_xor(mx, 16));
    mx = fmaxf(mx, __shfl_xor(mx, 32));
    float mnew = fmaxf(m, mx);
    float alpha = __expf(m - mnew);
    float ps = 0.f;
#pragma unroll
    for (int i = 0; i < 16; i++) {
      vals[i] = __expf(vals[i] - mnew);
      ps += vals[i];
    }
    ps += __shfl_xor(ps, 16);
    ps += __shfl_xor(ps, 32);
    l = l * alpha + ps;
    m = mnew;
    // rescale O (rows q=quad*4+r) by alpha(q) fetched cross-lane
#pragma unroll
    for (int r = 0; r < 4; r++) {
      float ar = __shfl(alpha, quad * 20 + r);  // lane quad*16 + (quad*4+r)
#pragma unroll
      for (int dt = 0; dt < 4; dt++) o[dt][r] *= ar;
    }

    // ---- store P[q=l16][kv] bf16 (packed b64), per-wave private ----
#pragma unroll
    for (int mt = 0; mt < 4; mt++) {
      ushort4 pw;
      pw.x = f2bf(vals[mt * 4 + 0]);
      pw.y = f2bf(vals[mt * 4 + 1]);
      pw.z = f2bf(vals[mt * 4 + 2]);
      pw.w = f2bf(vals[mt * 4 + 3]);
      *(ushort4*)&sP[wave][l16 * AP + mt * 16 + quad * 4] = pw;
    }

    // ---- O += P·V : A=P[q][kv], B=Vt[d][kv] ----
#pragma unroll
    for (int kc = 0; kc < 2; kc++) {
      short8 pa = *(const short8*)&sP[wave][l16 * AP + kc * 32 + quad * 8];
#pragma unroll
      for (int dt = 0; dt < 4; dt++) {
        short8 vb = *(const short8*)&sVt[(dt * 16 + l16) * AP + kc * 32 + quad * 8];
        o[dt] = __builtin_amdgcn_mfma_f32_16x16x32_bf16(pa, vb, o[dt], 0, 0, 0);
      }
    }
    __syncthreads();
  }

  // ---- epilogue: O rows q=quad*4+r, cols d=dt*16+l16 ----
  float il[4];
#pragma unroll
  for (int r = 0; r < 4; r++) il[r] = 1.0f / __shfl(l, quad * 20 + r);
  unsigned short* Yb = Y + (size_t)(bb * T_DIM + qbase) * C_DIM + h * HD;
#pragma unroll
  for (int dt = 0; dt < 4; dt++)
#pragma unroll
    for (int r = 0; r < 4; r++)
      Yb[(size_t)(quad * 4 + r) * C_DIM + dt * 16 + l16] = f2bf(o[dt][r] * il[r]);
}

extern "C" void kernel_launch(void* const* d_in, const int* in_sizes, int n_in,
                              void* d_out, int out_size, void* d_ws, size_t ws_size,
                              hipStream_t stream) {
  const float* x      = (const float*)d_in[0];
  const float* ln1_g  = (const float*)d_in[1];
  const float* ln1_b  = (const float*)d_in[2];
  const float* attn_w = (const float*)d_in[3];
  const float* attn_b = (const float*)d_in[4];
  const float* proj_w = (const float*)d_in[5];
  const float* proj_b = (const float*)d_in[6];
  const float* ln2_g  = (const float*)d_in[7];
  const float* ln2_b  = (const float*)d_in[8];
  const float* fc_w   = (const float*)d_in[9];
  const float* fc_b   = (const float*)d_in[10];
  const float* fc2_w  = (const float*)d_in[11];
  const float* fc2_b  = (const float*)d_in[12];

  char* ws = (char*)d_ws;
  unsigned short* wqkv_t  = (unsigned short*)(ws + 0);          // 6 MB
  unsigned short* wproj_t = (unsigned short*)(ws + 6291456);    // 2 MB
  unsigned short* wfc_t   = (unsigned short*)(ws + 8388608);    // 8 MB
  unsigned short* wfc2_t  = (unsigned short*)(ws + 16777216);   // 8 MB
  unsigned short* xn1     = (unsigned short*)(ws + 25165824);   // 8 MB (reused as xn2)
  unsigned short* qkv     = (unsigned short*)(ws + 33554432);   // 24 MB (32M..56M)
  unsigned short* y       = (unsigned short*)(ws + 58720256);   // 8 MB (56M..64M)
  unsigned short* hmid    = (unsigned short*)(ws + 33554432);   // 32 MB, aliases qkv+y (dead)
  unsigned short* xn2     = xn1;
  float* x1  = (float*)d_out;
  float* out = (float*)d_out;

  dim3 t32x8(32, 8);
  wt_kernel<<<dim3(3072 / 32, 1024 / 32), t32x8, 0, stream>>>(attn_w, wqkv_t, 1024, 3072);
  wt_kernel<<<dim3(1024 / 32, 1024 / 32), t32x8, 0, stream>>>(proj_w, wproj_t, 1024, 1024);
  wt_kernel<<<dim3(4096 / 32, 1024 / 32), t32x8, 0, stream>>>(fc_w, wfc_t, 1024, 4096);
  wt_kernel<<<dim3(1024 / 32, 4096 / 32), t32x8, 0, stream>>>(fc2_w, wfc2_t, 4096, 1024);

  ln_kernel<<<NTOK, 256, 0, stream>>>(x, ln1_g, ln1_b, xn1);
  gemm_bt<0, 1><<<dim3(3072 / 128, NTOK / 128), 256, 0, stream>>>(
      xn1, wqkv_t, attn_b, nullptr, qkv, NTOK, 3072, 1024);
  attn_mfma_kernel<<<dim3(T_DIM / 64, 32), 256, 0, stream>>>(qkv, y);
  gemm_bt<0, 0><<<dim3(1024 / 128, NTOK / 128), 256, 0, stream>>>(
      y, wproj_t, proj_b, x, (void*)x1, NTOK, 1024, 1024);
  ln_kernel<<<NTOK, 256, 0, stream>>>(x1, ln2_g, ln2_b, xn2);
  gemm_bt<1, 1><<<dim3(4096 / 128, NTOK / 128), 256, 0, stream>>>(
      xn2, wfc_t, fc_b, nullptr, hmid, NTOK, 4096, 1024);
  gemm_bt<0, 0><<<dim3(1024 / 128, NTOK / 128), 256, 0, stream>>>(
      hmid, wfc2_t, fc2_b, x1, (void*)out, NTOK, 1024, 4096);
}